// Round 13
// baseline (4808.295 us; speedup 1.0000x reference)
//
#include <hip/hip_runtime.h>
#include <cstdio>

#define N_NODES 100000
#define N_EDGES 220000
#define N_TOT   320000   // E + N self loops
#define N_B     4096
#define HIDDEN  256
#define CHUNK   12800
#define BN_S    0.9999950000374997f

// ---------------- staged debug probe (single thread) ----------------
__global__ void dbg_kernel(int stage, const void* pa,
                           const float* h, const float* xrc, const int* rowptr,
                           const int* brp, const float* gate, const float* pooled,
                           const float* r1, const float* r3) {
  if (threadIdx.x != 0 || blockIdx.x != 0) return;
  if (stage == 0) {
    const float* x = (const float*)pa;
    printf("MGDBG0 x: %f %f %f %f\n", x[0], x[1], x[2], x[3]);
  } else if (stage == 2) {
    const float* xp = (const float*)pa;
    printf("MGDBG2 xpad: %f %f %f | r1: %f %f | pad75: %f\n",
           xp[0], xp[1], xp[2], xp[96], xp[97], xp[75]);
  } else if (stage == 3) {
    printf("MGDBG3 h: %f %f %f %f\n", h[0], h[1], h[2], h[3]);
  } else if (stage == 4) {
    printf("MGDBG4 rowptr: %d %d %d rp[N]=%d | brp: %d %d %d\n",
           rowptr[0], rowptr[1], rowptr[2], rowptr[N_NODES], brp[0], brp[1], brp[2]);
  } else if (stage == 5) {
    printf("MGDBG5 h_final: %f %f %f %f | h[1000*256]=%f\n",
           h[0], h[1], h[2], h[3], h[256000]);
  } else if (stage == 6) {
    printf("MGDBG6 gate: %f %f %f | pooled: %f %f %f %f\n",
           gate[0], gate[1], gate[2], pooled[0], pooled[1], pooled[2], pooled[3]);
  } else if (stage == 7) {
    printf("MGDBG7 r1: %f %f | r3: %f %f\n", r1[0], r1[1], r3[0], r3[1]);
  } else if (stage == 9) {
    const float* of = (const float*)pa;
    const unsigned short* ou = (const unsigned short*)pa;
    printf("MGDBG9 dout f32: %f %f %f | u16: %u %u %u %u\n",
           of[0], of[1], of[2], (unsigned)ou[0], (unsigned)ou[1], (unsigned)ou[2], (unsigned)ou[3]);
  }
}

// ---------------- zero-init of counters ----------------
__global__ void zero_kernel(int* __restrict__ deg, int* __restrict__ cursor, float* __restrict__ macc) {
  int i = blockIdx.x * blockDim.x + threadIdx.x;
  if (i < N_NODES) { deg[i] = 0; cursor[i] = 0; }
  if (i < 16) macc[i] = 0.f;
}

// ---------------- mean of edge_attr (f32 [E,10]) ----------------
__global__ void mean_kernel(const float* __restrict__ ea, float* __restrict__ macc) {
  int lane = threadIdx.x & 63;
  float loc[10];
#pragma unroll
  for (int k = 0; k < 10; ++k) loc[k] = 0.f;
  for (int e = blockIdx.x * blockDim.x + threadIdx.x; e < N_EDGES; e += gridDim.x * blockDim.x) {
    const float* p = ea + (size_t)e * 10;
#pragma unroll
    for (int k = 0; k < 10; ++k) loc[k] += p[k];
  }
#pragma unroll
  for (int k = 0; k < 10; ++k) {
    float v = loc[k];
#pragma unroll
    for (int o = 1; o < 64; o <<= 1) v += __shfl_xor(v, o);
    if (lane == 0) atomicAdd(&macc[k], v);
  }
}

__global__ void epself_kernel(const float* __restrict__ macc, const float* __restrict__ We,
                              float* __restrict__ ep_self) {
  int i = blockIdx.x;
  int c = threadIdx.x;
  const float invE = 1.f / (float)N_EDGES;
  float s = 0.f;
#pragma unroll
  for (int k = 0; k < 10; ++k)
    s += (macc[k] * invE) * We[(size_t)i * 2560 + k * 256 + c];
  ep_self[i * 256 + c] = s;
}

// ---------------- CSR build (by target) ----------------
__global__ void count_kernel(const int* __restrict__ ei, int* __restrict__ deg) {
  for (int e = blockIdx.x * blockDim.x + threadIdx.x; e < N_TOT; e += gridDim.x * blockDim.x) {
    int t;
    if (e < N_EDGES) t = ei[N_EDGES + e];
    else             t = e - N_EDGES;
    atomicAdd(&deg[t], 1);
  }
}

__global__ __launch_bounds__(1024) void scan_kernel(const int* __restrict__ deg, int* __restrict__ rowptr) {
  __shared__ int buf[1024];
  __shared__ int carry;
  int t = threadIdx.x;
  if (t == 0) { rowptr[0] = 0; carry = 0; }
  __syncthreads();
  for (int base = 0; base < N_NODES; base += 1024) {
    int i = base + t;
    int v = (i < N_NODES) ? deg[i] : 0;
    buf[t] = v;
    __syncthreads();
    for (int off = 1; off < 1024; off <<= 1) {
      int add = (t >= off) ? buf[t - off] : 0;
      __syncthreads();
      buf[t] += add;
      __syncthreads();
    }
    int outv = buf[t] + carry;
    if (i < N_NODES) rowptr[i + 1] = outv;
    __syncthreads();
    if (t == 1023) carry = outv;
    __syncthreads();
  }
}

__global__ void scatter_kernel(const int* __restrict__ ei, const int* __restrict__ rowptr,
                               int* __restrict__ cursor, int* __restrict__ csr) {
  for (int e = blockIdx.x * blockDim.x + threadIdx.x; e < N_TOT; e += gridDim.x * blockDim.x) {
    int t;
    if (e < N_EDGES) t = ei[N_EDGES + e];
    else             t = e - N_EDGES;
    int pos = atomicAdd(&cursor[t], 1);
    csr[rowptr[t] + pos] = e;
  }
}

__global__ void brp_kernel(const int* __restrict__ batch, int* __restrict__ brp) {
  for (int i = blockIdx.x * blockDim.x + threadIdx.x; i < N_NODES; i += gridDim.x * blockDim.x) {
    int bi = batch[i];
    int bp = (i == 0) ? -1 : batch[i - 1];
    for (int b = bp + 1; b <= bi; ++b) brp[b] = i;
    if (i == N_NODES - 1) {
      for (int b = bi + 1; b <= N_B; ++b) brp[b] = N_NODES;
    }
  }
}

// ---------------- x -> padded f32 [N,96] ----------------
__global__ void convx_kernel(const float* __restrict__ x, float* __restrict__ xp) {
  int total = N_NODES * 96;
  for (int idx = blockIdx.x * blockDim.x + threadIdx.x; idx < total; idx += gridDim.x * blockDim.x) {
    int nn = idx / 96;
    int j = idx - nn * 96;
    float v = 0.f;
    if (j < 75) v = x[(size_t)nn * 75 + j];
    xp[idx] = v;
  }
}

// ---------------- generic f32 GEMM ----------------
__global__ __launch_bounds__(256) void gemm_kernel(
    const float* __restrict__ A, const float* __restrict__ B,
    const float* __restrict__ bias, float* __restrict__ C,
    int M, int Ncol, int K, int KB, int act, float scale)
{
  __shared__ float As[32][68];
  __shared__ float Bs[32][68];
  const int tid = threadIdx.x;
  const int tx = tid & 15, ty = tid >> 4;
  const int col0 = blockIdx.x * 64;
  const int row0 = blockIdx.y * 64;
  float acc[4][4];
#pragma unroll
  for (int i = 0; i < 4; ++i)
#pragma unroll
    for (int j = 0; j < 4; ++j) acc[i][j] = 0.f;

  const int ar = tid >> 3;
  const int ak = (tid & 7) * 4;
  const int bk = tid >> 4;
  const int bc = (tid & 15) * 4;

  for (int k0 = 0; k0 < K; k0 += 32) {
#pragma unroll
    for (int p = 0; p < 2; ++p) {
      int r = ar + p * 32;
      int grow = row0 + r;
      float4 v = make_float4(0.f, 0.f, 0.f, 0.f);
      if (grow < M) v = *(const float4*)(A + (size_t)grow * K + k0 + ak);
      As[ak + 0][r] = v.x; As[ak + 1][r] = v.y; As[ak + 2][r] = v.z; As[ak + 3][r] = v.w;
    }
#pragma unroll
    for (int p = 0; p < 2; ++p) {
      int kk = bk + p * 16;
      float4 v = make_float4(0.f, 0.f, 0.f, 0.f);
      if (k0 + kk < KB) v = *(const float4*)(B + (size_t)(k0 + kk) * Ncol + col0 + bc);
      *(float4*)(&Bs[kk][bc]) = v;
    }
    __syncthreads();
#pragma unroll
    for (int kk = 0; kk < 32; ++kk) {
      float4 a = *(const float4*)(&As[kk][ty * 4]);
      float4 b = *(const float4*)(&Bs[kk][tx * 4]);
      float av[4] = {a.x, a.y, a.z, a.w};
      float bv[4] = {b.x, b.y, b.z, b.w};
#pragma unroll
      for (int i = 0; i < 4; ++i)
#pragma unroll
        for (int j = 0; j < 4; ++j) acc[i][j] = fmaf(av[i], bv[j], acc[i][j]);
    }
    __syncthreads();
  }
  float bvals[4] = {0.f, 0.f, 0.f, 0.f};
  if (bias) {
#pragma unroll
    for (int j = 0; j < 4; ++j) bvals[j] = bias[col0 + tx * 4 + j];
  }
#pragma unroll
  for (int i = 0; i < 4; ++i) {
    int r = row0 + ty * 4 + i;
    if (r >= M) continue;
    float4 outv;
    float* o = (float*)&outv;
#pragma unroll
    for (int j = 0; j < 4; ++j) {
      float v = (acc[i][j] + bvals[j]) * scale;
      if (act == 1) v = fmaxf(v, 0.f);
      else if (act == 2) v = (v > 0.f) ? v : (__expf(v) - 1.f);
      o[j] = v;
    }
    *(float4*)(C + (size_t)r * Ncol + col0 + tx * 4) = outv;
  }
}

// ---------------- fused GATv2 attention ----------------
__global__ __launch_bounds__(256) void attn_kernel(
    const float* __restrict__ xl, const float* __restrict__ xrc,
    int base, int mcnt, float* __restrict__ h,
    const int* __restrict__ ei, const float* __restrict__ eattr,
    const float* __restrict__ We, const float* __restrict__ att,
    const float* __restrict__ bgat, const float* __restrict__ ep_self,
    const int* __restrict__ rowptr, const int* __restrict__ csr)
{
  const int lane = threadIdx.x & 63;
  const int wv = threadIdx.x >> 6;
  const int li = blockIdx.x * 4 + wv;
  if (li >= mcnt) return;
  const int n = base + li;
  const int c0 = lane * 4;

  float4 xrn = *(const float4*)(xrc + (size_t)li * HIDDEN + c0);
  float4 attf4 = *(const float4*)(att + c0);
  float attf[4] = {attf4.x, attf4.y, attf4.z, attf4.w};
  float wef[10][4];
#pragma unroll
  for (int k = 0; k < 10; ++k) {
    float4 w4 = *(const float4*)(We + k * 256 + c0);
    wef[k][0] = w4.x; wef[k][1] = w4.y; wef[k][2] = w4.z; wef[k][3] = w4.w;
  }
  float4 eps = *(const float4*)(ep_self + c0);

  float m = -__builtin_inff();
  float d = 0.f;
  float a0 = 0.f, a1 = 0.f, a2 = 0.f, a3 = 0.f;
  const int s = rowptr[n], e = rowptr[n + 1];
  for (int idx = s; idx < e; ++idx) {
    int eid = csr[idx];
    int srcn;
    float ep0, ep1, ep2, ep3;
    if (eid < N_EDGES) {
      srcn = ei[eid];
      const float* eap = eattr + (size_t)eid * 10;
      ep0 = 0.f; ep1 = 0.f; ep2 = 0.f; ep3 = 0.f;
#pragma unroll
      for (int k = 0; k < 10; ++k) {
        float eak = eap[k];
        ep0 = fmaf(eak, wef[k][0], ep0);
        ep1 = fmaf(eak, wef[k][1], ep1);
        ep2 = fmaf(eak, wef[k][2], ep2);
        ep3 = fmaf(eak, wef[k][3], ep3);
      }
    } else {
      srcn = eid - N_EDGES;
      ep0 = eps.x; ep1 = eps.y; ep2 = eps.z; ep3 = eps.w;
    }
    float4 xls = *(const float4*)(xl + (size_t)srcn * HIDDEN + c0);
    float s0 = xls.x + xrn.x + ep0;
    float s1 = xls.y + xrn.y + ep1;
    float s2 = xls.z + xrn.z + ep2;
    float s3 = xls.w + xrn.w + ep3;
    s0 = (s0 > 0.f) ? s0 : 0.2f * s0;
    s1 = (s1 > 0.f) ? s1 : 0.2f * s1;
    s2 = (s2 > 0.f) ? s2 : 0.2f * s2;
    s3 = (s3 > 0.f) ? s3 : 0.2f * s3;
    float part = s0 * attf[0] + s1 * attf[1] + s2 * attf[2] + s3 * attf[3];
    part += __shfl_xor(part, 1);
    part += __shfl_xor(part, 2);
    part += __shfl_xor(part, 4);
    float logit = part;
    float mn = fmaxf(m, logit);
    float sc = __expf(m - mn);
    float w = __expf(logit - mn);
    d = d * sc + w;
    a0 = a0 * sc + w * xls.x;
    a1 = a1 * sc + w * xls.y;
    a2 = a2 * sc + w * xls.z;
    a3 = a3 * sc + w * xls.w;
    m = mn;
  }
  float inv = 1.f / (d + 1e-16f);
  float4 bg = *(const float4*)(bgat + c0);
  float4 hold = *(const float4*)(h + (size_t)n * HIDDEN + c0);
  float ov[4] = {a0 * inv, a1 * inv, a2 * inv, a3 * inv};
  float bgv[4] = {bg.x, bg.y, bg.z, bg.w};
  float hv[4] = {hold.x, hold.y, hold.z, hold.w};
  float4 res;
  float* rp = (float*)&res;
#pragma unroll
  for (int j = 0; j < 4; ++j) {
    float v = (ov[j] + bgv[j]) * BN_S;
    v = (v > 0.f) ? v : (__expf(v) - 1.f);
    rp[j] = v + hv[j];
  }
  *(float4*)(h + (size_t)n * HIDDEN + c0) = res;
}

// ---------------- gate (chunked) ----------------
__global__ __launch_bounds__(256) void gate_kernel(
    const float* __restrict__ g1c, int base, int mcnt,
    const float* __restrict__ Wg2, const float* __restrict__ bg2,
    float* __restrict__ gate)
{
  int lane = threadIdx.x & 63;
  int wv = threadIdx.x >> 6;
  int stride = gridDim.x * 4;
  float w0 = Wg2[lane];
  float w1 = Wg2[64 + lane];
  float bb = bg2[0];
  for (int li = blockIdx.x * 4 + wv; li < mcnt; li += stride) {
    float v = g1c[(size_t)li * 128 + lane] * w0 + g1c[(size_t)li * 128 + 64 + lane] * w1;
#pragma unroll
    for (int o = 1; o < 64; o <<= 1) v += __shfl_xor(v, o);
    if (lane == 0) gate[base + li] = v + bb;
  }
}

// ---------------- pooling ----------------
__global__ __launch_bounds__(64) void pool_kernel(
    const float* __restrict__ gate, const float* __restrict__ h,
    const int* __restrict__ brp, float* __restrict__ pooled)
{
  int b = blockIdx.x;
  int lane = threadIdx.x;
  int s = brp[b], e = brp[b + 1];
  float m = -__builtin_inff();
  for (int i = s + lane; i < e; i += 64) m = fmaxf(m, gate[i]);
#pragma unroll
  for (int o = 1; o < 64; o <<= 1) m = fmaxf(m, __shfl_xor(m, o));
  float d = 0.f;
  for (int i = s + lane; i < e; i += 64) d += __expf(gate[i] - m);
#pragma unroll
  for (int o = 1; o < 64; o <<= 1) d += __shfl_xor(d, o);
  float inv = 1.f / (d + 1e-16f);
  int c0 = lane * 4;
  float acc[4] = {0.f, 0.f, 0.f, 0.f};
  for (int i = s; i < e; ++i) {
    float w = __expf(gate[i] - m) * inv;
    float4 hv = *(const float4*)(h + (size_t)i * HIDDEN + c0);
    acc[0] = fmaf(w, hv.x, acc[0]);
    acc[1] = fmaf(w, hv.y, acc[1]);
    acc[2] = fmaf(w, hv.z, acc[2]);
    acc[3] = fmaf(w, hv.w, acc[3]);
  }
  float4 outv = make_float4(acc[0], acc[1], acc[2], acc[3]);
  *(float4*)(pooled + (size_t)b * HIDDEN + c0) = outv;
}

// ---------------- final: out[b] = r3[b,:] . W4 + b4 (f32 store) ----------------
__global__ __launch_bounds__(256) void out_kernel(
    const float* __restrict__ r3, const float* __restrict__ W4,
    const float* __restrict__ b4, float* __restrict__ out)
{
  int lane = threadIdx.x & 63;
  int wv = threadIdx.x >> 6;
  int b = blockIdx.x * 4 + wv;
  if (b >= N_B) return;
  float v = r3[(size_t)b * 64 + lane] * W4[lane];
#pragma unroll
  for (int o = 1; o < 64; o <<= 1) v += __shfl_xor(v, o);
  if (lane == 0) {
    float r = v + b4[0];
    if (b == 0) printf("MGDBG8 out0=%f out1计...\n", r);
    out[b] = r;
  }
}

extern "C" void kernel_launch(void* const* d_in, const int* in_sizes, int n_in,
                              void* d_out, int out_size, void* d_ws, size_t ws_size,
                              hipStream_t stream)
{
  const float* x    = (const float*)d_in[0];
  const int* ei     = (const int*)d_in[1];
  const float* ea   = (const float*)d_in[2];
  const int* batch  = (const int*)d_in[3];
  const float* W_in = (const float*)d_in[4];
  const float* b_in = (const float*)d_in[5];
  const float* Wl   = (const float*)d_in[6];
  const float* Wr   = (const float*)d_in[7];
  const float* We   = (const float*)d_in[8];
  const float* att  = (const float*)d_in[9];
  const float* bgat = (const float*)d_in[10];
  const float* Wg1  = (const float*)d_in[11];
  const float* bg1  = (const float*)d_in[12];
  const float* Wg2  = (const float*)d_in[13];
  const float* bg2  = (const float*)d_in[14];
  const float* W1   = (const float*)d_in[15];
  const float* b1   = (const float*)d_in[16];
  const float* W2   = (const float*)d_in[17];
  const float* b2   = (const float*)d_in[18];
  const float* W3   = (const float*)d_in[19];
  const float* b3   = (const float*)d_in[20];
  const float* W4   = (const float*)d_in[21];
  const float* b4   = (const float*)d_in[22];
  float* out = (float*)d_out;

  char* ws = (char*)d_ws;
  size_t off = 0;
  auto alloc = [&](size_t bytes) -> char* {
    char* p = ws + off;
    off += (bytes + 255) & ~(size_t)255;
    return p;
  };
  float* h       = (float*)alloc((size_t)N_NODES * HIDDEN * 4);
  float* xl      = (float*)alloc((size_t)N_NODES * HIDDEN * 4);
  float* xrc     = (float*)alloc((size_t)CHUNK * HIDDEN * 4);
  int* deg       = (int*)alloc((size_t)N_NODES * 4);
  int* rowptr    = (int*)alloc((size_t)(N_NODES + 1) * 4);
  int* cursor    = (int*)alloc((size_t)N_NODES * 4);
  int* csr       = (int*)alloc((size_t)N_TOT * 4);
  int* brp       = (int*)alloc((size_t)(N_B + 1) * 4);
  float* macc    = (float*)alloc(64);
  float* ep_self = (float*)alloc(4 * 256 * 4);
  float* pooled  = (float*)alloc((size_t)N_B * HIDDEN * 4);
  float* r1      = (float*)alloc((size_t)N_B * 256 * 4);
  float* r2      = (float*)alloc((size_t)N_B * 128 * 4);
  float* r3      = (float*)alloc((size_t)N_B * 64 * 4);

  float* xpad = xl;
  float* g1c  = xrc;
  float* gate = xl;

  fprintf(stderr, "MGDIAG r13 ws_size=%zu need=%zu out_size=%d\n", ws_size, off, out_size);
  fflush(stderr);
  printf("MGDIAG r13 ws_size=%zu need=%zu out_size=%d\n", ws_size, off, out_size);
  fflush(stdout);

  zero_kernel<<<391, 256, 0, stream>>>(deg, cursor, macc);
  mean_kernel<<<256, 256, 0, stream>>>(ea, macc);
  epself_kernel<<<4, 256, 0, stream>>>(macc, We, ep_self);
  count_kernel<<<1250, 256, 0, stream>>>(ei, deg);
  scan_kernel<<<1, 1024, 0, stream>>>(deg, rowptr);
  scatter_kernel<<<1250, 256, 0, stream>>>(ei, rowptr, cursor, csr);
  brp_kernel<<<512, 256, 0, stream>>>(batch, brp);
  convx_kernel<<<4096, 256, 0, stream>>>(x, xpad);

  dbg_kernel<<<1, 64, 0, stream>>>(0, x, h, xrc, rowptr, brp, gate, pooled, r1, r3);
  dbg_kernel<<<1, 64, 0, stream>>>(2, xpad, h, xrc, rowptr, brp, gate, pooled, r1, r3);
  dbg_kernel<<<1, 64, 0, stream>>>(4, x, h, xrc, rowptr, brp, gate, pooled, r1, r3);

  gemm_kernel<<<dim3(4, 1563), 256, 0, stream>>>(xpad, W_in, b_in, h, N_NODES, 256, 96, 75, 2, BN_S);
  dbg_kernel<<<1, 64, 0, stream>>>(3, x, h, xrc, rowptr, brp, gate, pooled, r1, r3);

  for (int i = 0; i < 4; ++i) {
    gemm_kernel<<<dim3(4, 1563), 256, 0, stream>>>(h, Wl + (size_t)i * 65536, nullptr, xl,
                                                   N_NODES, 256, 256, 256, 0, 1.f);
    for (int base = 0; base < N_NODES; base += CHUNK) {
      int m = (N_NODES - base < CHUNK) ? (N_NODES - base) : CHUNK;
      gemm_kernel<<<dim3(4, (m + 63) / 64), 256, 0, stream>>>(
          h + (size_t)base * HIDDEN, Wr + (size_t)i * 65536, nullptr, xrc,
          m, 256, 256, 256, 0, 1.f);
      attn_kernel<<<(m + 3) / 4, 256, 0, stream>>>(
          xl, xrc, base, m, h, ei, ea,
          We + (size_t)i * 2560, att + (size_t)i * 256,
          bgat + (size_t)i * 256, ep_self + (size_t)i * 256,
          rowptr, csr);
    }
  }
  dbg_kernel<<<1, 64, 0, stream>>>(5, x, h, xrc, rowptr, brp, gate, pooled, r1, r3);

  for (int base = 0; base < N_NODES; base += CHUNK) {
    int m = (N_NODES - base < CHUNK) ? (N_NODES - base) : CHUNK;
    gemm_kernel<<<dim3(2, (m + 63) / 64), 256, 0, stream>>>(
        h + (size_t)base * HIDDEN, Wg1, bg1, g1c, m, 128, 256, 256, 1, 1.f);
    gate_kernel<<<200, 256, 0, stream>>>(g1c, base, m, Wg2, bg2, gate);
  }
  pool_kernel<<<N_B, 64, 0, stream>>>(gate, h, brp, pooled);
  dbg_kernel<<<1, 64, 0, stream>>>(6, x, h, xrc, rowptr, brp, gate, pooled, r1, r3);

  gemm_kernel<<<dim3(4, 64), 256, 0, stream>>>(pooled, W1, b1, r1, N_B, 256, 256, 256, 1, BN_S);
  gemm_kernel<<<dim3(2, 64), 256, 0, stream>>>(r1, W2, b2, r2, N_B, 128, 256, 256, 1, BN_S);
  gemm_kernel<<<dim3(1, 64), 256, 0, stream>>>(r2, W3, b3, r3, N_B, 64, 128, 128, 1, 1.f);
  dbg_kernel<<<1, 64, 0, stream>>>(7, x, h, xrc, rowptr, brp, gate, pooled, r1, r3);
  out_kernel<<<1024, 256, 0, stream>>>(r3, W4, b4, out);
  dbg_kernel<<<1, 64, 0, stream>>>(9, d_out, h, xrc, rowptr, brp, gate, pooled, r1, r3);

  hipError_t e = hipGetLastError();
  fprintf(stderr, "MGDIAG r13 lasterr=%d (%s)\n", (int)e, hipGetErrorString(e)); fflush(stderr);
  printf("MGDIAG r13 lasterr=%d (%s)\n", (int)e, hipGetErrorString(e)); fflush(stdout);
}

// Round 14
// 2713.978 us; speedup vs baseline: 1.7717x; 1.7717x over previous
//
#include <hip/hip_runtime.h>

#define N_NODES 100000
#define N_EDGES 220000
#define N_TOT   320000   // E + N self loops
#define N_B     4096
#define HIDDEN  256
#define BN_S    0.9999950000374997f

__device__ __forceinline__ float bf2f(unsigned short u) {
  return __uint_as_float(((unsigned int)u) << 16);
}
__device__ __forceinline__ unsigned short f2bf(float f) {
  unsigned int x = __float_as_uint(f);
  unsigned int lsb = (x >> 16) & 1u;
  x += 0x7fffu + lsb;
  return (unsigned short)(x >> 16);
}

// ---------------- zero-init of counters (ws poisoned 0xAA each launch) ----------------
__global__ void zero_kernel(int* __restrict__ deg, int* __restrict__ cursor, float* __restrict__ macc) {
  int i = blockIdx.x * blockDim.x + threadIdx.x;
  if (i < N_NODES) { deg[i] = 0; cursor[i] = 0; }
  if (i < 16) macc[i] = 0.f;
}

// ---------------- mean of edge_attr (f32 [E,10]) ----------------
__global__ void mean_kernel(const float* __restrict__ ea, float* __restrict__ macc) {
  int lane = threadIdx.x & 63;
  float loc[10];
#pragma unroll
  for (int k = 0; k < 10; ++k) loc[k] = 0.f;
  for (int e = blockIdx.x * blockDim.x + threadIdx.x; e < N_EDGES; e += gridDim.x * blockDim.x) {
    const float* p = ea + (size_t)e * 10;
#pragma unroll
    for (int k = 0; k < 10; ++k) loc[k] += p[k];
  }
#pragma unroll
  for (int k = 0; k < 10; ++k) {
    float v = loc[k];
#pragma unroll
    for (int o = 1; o < 64; o <<= 1) v += __shfl_xor(v, o);
    if (lane == 0) atomicAdd(&macc[k], v);
  }
}

__global__ void epself_kernel(const float* __restrict__ macc, const float* __restrict__ We,
                              float* __restrict__ ep_self) {
  int i = blockIdx.x;
  int c = threadIdx.x;
  const float invE = 1.f / (float)N_EDGES;
  float s = 0.f;
#pragma unroll
  for (int k = 0; k < 10; ++k)
    s += (macc[k] * invE) * We[(size_t)i * 2560 + k * 256 + c];
  ep_self[i * 256 + c] = s;
}

// ---------------- CSR build (by target) ----------------
__global__ void count_kernel(const int* __restrict__ ei, int* __restrict__ deg) {
  for (int e = blockIdx.x * blockDim.x + threadIdx.x; e < N_TOT; e += gridDim.x * blockDim.x) {
    int t;
    if (e < N_EDGES) t = ei[N_EDGES + e];
    else             t = e - N_EDGES;
    atomicAdd(&deg[t], 1);
  }
}

__global__ __launch_bounds__(1024) void scan_kernel(const int* __restrict__ deg, int* __restrict__ rowptr) {
  __shared__ int buf[1024];
  __shared__ int carry;
  int t = threadIdx.x;
  if (t == 0) { rowptr[0] = 0; carry = 0; }
  __syncthreads();
  for (int base = 0; base < N_NODES; base += 1024) {
    int i = base + t;
    int v = (i < N_NODES) ? deg[i] : 0;
    buf[t] = v;
    __syncthreads();
    for (int off = 1; off < 1024; off <<= 1) {
      int add = (t >= off) ? buf[t - off] : 0;
      __syncthreads();
      buf[t] += add;
      __syncthreads();
    }
    int outv = buf[t] + carry;
    if (i < N_NODES) rowptr[i + 1] = outv;
    __syncthreads();
    if (t == 1023) carry = outv;
    __syncthreads();
  }
}

__global__ void scatter_kernel(const int* __restrict__ ei, const int* __restrict__ rowptr,
                               int* __restrict__ cursor, int* __restrict__ csr) {
  for (int e = blockIdx.x * blockDim.x + threadIdx.x; e < N_TOT; e += gridDim.x * blockDim.x) {
    int t;
    if (e < N_EDGES) t = ei[N_EDGES + e];
    else             t = e - N_EDGES;
    int pos = atomicAdd(&cursor[t], 1);
    csr[rowptr[t] + pos] = e;
  }
}

__global__ void brp_kernel(const int* __restrict__ batch, int* __restrict__ brp) {
  for (int i = blockIdx.x * blockDim.x + threadIdx.x; i < N_NODES; i += gridDim.x * blockDim.x) {
    int bi = batch[i];
    int bp = (i == 0) ? -1 : batch[i - 1];
    for (int b = bp + 1; b <= bi; ++b) brp[b] = i;
    if (i == N_NODES - 1) {
      for (int b = bi + 1; b <= N_B; ++b) brp[b] = N_NODES;
    }
  }
}

// ---------------- x -> padded f32 [N,96] ----------------
__global__ void convx_kernel(const float* __restrict__ x, float* __restrict__ xp) {
  int total = N_NODES * 96;
  for (int idx = blockIdx.x * blockDim.x + threadIdx.x; idx < total; idx += gridDim.x * blockDim.x) {
    int nn = idx / 96;
    int j = idx - nn * 96;
    float v = 0.f;
    if (j < 75) v = x[(size_t)nn * 75 + j];
    xp[idx] = v;
  }
}

// ---------------- generic f32 GEMM; C store f32 or bf16 ----------------
// C[M,Ncol] = act((A[M,K] @ B[K,Ncol] + bias) * scale); act 0=none 1=relu 2=elu
__global__ __launch_bounds__(256) void gemm_kernel(
    const float* __restrict__ A, const float* __restrict__ B,
    const float* __restrict__ bias, void* __restrict__ C,
    int M, int Ncol, int K, int KB, int act, float scale, int obf16)
{
  __shared__ float As[32][68];
  __shared__ float Bs[32][68];
  const int tid = threadIdx.x;
  const int tx = tid & 15, ty = tid >> 4;
  const int col0 = blockIdx.x * 64;
  const int row0 = blockIdx.y * 64;
  float acc[4][4];
#pragma unroll
  for (int i = 0; i < 4; ++i)
#pragma unroll
    for (int j = 0; j < 4; ++j) acc[i][j] = 0.f;

  const int ar = tid >> 3;
  const int ak = (tid & 7) * 4;
  const int bk = tid >> 4;
  const int bc = (tid & 15) * 4;

  for (int k0 = 0; k0 < K; k0 += 32) {
#pragma unroll
    for (int p = 0; p < 2; ++p) {
      int r = ar + p * 32;
      int grow = row0 + r;
      float4 v = make_float4(0.f, 0.f, 0.f, 0.f);
      if (grow < M) v = *(const float4*)(A + (size_t)grow * K + k0 + ak);
      As[ak + 0][r] = v.x; As[ak + 1][r] = v.y; As[ak + 2][r] = v.z; As[ak + 3][r] = v.w;
    }
#pragma unroll
    for (int p = 0; p < 2; ++p) {
      int kk = bk + p * 16;
      float4 v = make_float4(0.f, 0.f, 0.f, 0.f);
      if (k0 + kk < KB) v = *(const float4*)(B + (size_t)(k0 + kk) * Ncol + col0 + bc);
      *(float4*)(&Bs[kk][bc]) = v;
    }
    __syncthreads();
#pragma unroll
    for (int kk = 0; kk < 32; ++kk) {
      float4 a = *(const float4*)(&As[kk][ty * 4]);
      float4 b = *(const float4*)(&Bs[kk][tx * 4]);
      float av[4] = {a.x, a.y, a.z, a.w};
      float bv[4] = {b.x, b.y, b.z, b.w};
#pragma unroll
      for (int i = 0; i < 4; ++i)
#pragma unroll
        for (int j = 0; j < 4; ++j) acc[i][j] = fmaf(av[i], bv[j], acc[i][j]);
    }
    __syncthreads();
  }
  float bvals[4] = {0.f, 0.f, 0.f, 0.f};
  if (bias) {
#pragma unroll
    for (int j = 0; j < 4; ++j) bvals[j] = bias[col0 + tx * 4 + j];
  }
#pragma unroll
  for (int i = 0; i < 4; ++i) {
    int r = row0 + ty * 4 + i;
    if (r >= M) continue;
    float ov[4];
#pragma unroll
    for (int j = 0; j < 4; ++j) {
      float v = (acc[i][j] + bvals[j]) * scale;
      if (act == 1) v = fmaxf(v, 0.f);
      else if (act == 2) v = (v > 0.f) ? v : (__expf(v) - 1.f);
      ov[j] = v;
    }
    if (obf16) {
      ushort4 o4;
      o4.x = f2bf(ov[0]); o4.y = f2bf(ov[1]); o4.z = f2bf(ov[2]); o4.w = f2bf(ov[3]);
      *(ushort4*)((unsigned short*)C + (size_t)r * Ncol + col0 + tx * 4) = o4;
    } else {
      float4 o4 = make_float4(ov[0], ov[1], ov[2], ov[3]);
      *(float4*)((float*)C + (size_t)r * Ncol + col0 + tx * 4) = o4;
    }
  }
}

// ---------------- fused GATv2 attention + aggregate + BN/ELU/residual ----------------
// one wave per node; lane l owns flat channels [4l,4l+4); head = l>>3
__global__ __launch_bounds__(256) void attn_kernel(
    const float* __restrict__ xl, const unsigned short* __restrict__ xr,
    float* __restrict__ h,
    const int* __restrict__ ei, const float* __restrict__ eattr,
    const float* __restrict__ We, const float* __restrict__ att,
    const float* __restrict__ bgat, const float* __restrict__ ep_self,
    const int* __restrict__ rowptr, const int* __restrict__ csr)
{
  const int lane = threadIdx.x & 63;
  const int wv = threadIdx.x >> 6;
  const int n = blockIdx.x * 4 + wv;
  if (n >= N_NODES) return;
  const int c0 = lane * 4;

  float xrn[4];
  {
    ushort4 u = *(const ushort4*)(xr + (size_t)n * HIDDEN + c0);
    xrn[0] = bf2f(u.x); xrn[1] = bf2f(u.y); xrn[2] = bf2f(u.z); xrn[3] = bf2f(u.w);
  }
  float4 attf4 = *(const float4*)(att + c0);
  float attf[4] = {attf4.x, attf4.y, attf4.z, attf4.w};
  float wef[10][4];
#pragma unroll
  for (int k = 0; k < 10; ++k) {
    float4 w4 = *(const float4*)(We + k * 256 + c0);
    wef[k][0] = w4.x; wef[k][1] = w4.y; wef[k][2] = w4.z; wef[k][3] = w4.w;
  }
  float4 eps = *(const float4*)(ep_self + c0);

  float m = -__builtin_inff();
  float d = 0.f;
  float a0 = 0.f, a1 = 0.f, a2 = 0.f, a3 = 0.f;
  const int s = rowptr[n], e = rowptr[n + 1];
  for (int idx = s; idx < e; ++idx) {
    int eid = csr[idx];
    int srcn;
    float ep0, ep1, ep2, ep3;
    if (eid < N_EDGES) {
      srcn = ei[eid];
      const float* eap = eattr + (size_t)eid * 10;
      ep0 = 0.f; ep1 = 0.f; ep2 = 0.f; ep3 = 0.f;
#pragma unroll
      for (int k = 0; k < 10; ++k) {
        float eak = eap[k];
        ep0 = fmaf(eak, wef[k][0], ep0);
        ep1 = fmaf(eak, wef[k][1], ep1);
        ep2 = fmaf(eak, wef[k][2], ep2);
        ep3 = fmaf(eak, wef[k][3], ep3);
      }
    } else {
      srcn = eid - N_EDGES;
      ep0 = eps.x; ep1 = eps.y; ep2 = eps.z; ep3 = eps.w;
    }
    float4 xls = *(const float4*)(xl + (size_t)srcn * HIDDEN + c0);
    float s0 = xls.x + xrn[0] + ep0;
    float s1 = xls.y + xrn[1] + ep1;
    float s2 = xls.z + xrn[2] + ep2;
    float s3 = xls.w + xrn[3] + ep3;
    s0 = (s0 > 0.f) ? s0 : 0.2f * s0;
    s1 = (s1 > 0.f) ? s1 : 0.2f * s1;
    s2 = (s2 > 0.f) ? s2 : 0.2f * s2;
    s3 = (s3 > 0.f) ? s3 : 0.2f * s3;
    float part = s0 * attf[0] + s1 * attf[1] + s2 * attf[2] + s3 * attf[3];
    part += __shfl_xor(part, 1);
    part += __shfl_xor(part, 2);
    part += __shfl_xor(part, 4);
    float logit = part;                     // per-head (8-lane group)
    float mn = fmaxf(m, logit);
    float sc = __expf(m - mn);              // m=-inf first iter -> 0
    float w = __expf(logit - mn);
    d = d * sc + w;
    a0 = a0 * sc + w * xls.x;
    a1 = a1 * sc + w * xls.y;
    a2 = a2 * sc + w * xls.z;
    a3 = a3 * sc + w * xls.w;
    m = mn;
  }
  float inv = 1.f / (d + 1e-16f);
  float4 bg = *(const float4*)(bgat + c0);
  float4 hold = *(const float4*)(h + (size_t)n * HIDDEN + c0);
  float ov[4] = {a0 * inv, a1 * inv, a2 * inv, a3 * inv};
  float bgv[4] = {bg.x, bg.y, bg.z, bg.w};
  float hv[4] = {hold.x, hold.y, hold.z, hold.w};
  float4 res;
  float* rp = (float*)&res;
#pragma unroll
  for (int j = 0; j < 4; ++j) {
    float v = (ov[j] + bgv[j]) * BN_S;
    v = (v > 0.f) ? v : (__expf(v) - 1.f);
    rp[j] = v + hv[j];
  }
  *(float4*)(h + (size_t)n * HIDDEN + c0) = res;
}

// ---------------- gate = relu_g1 @ Wg2 + bg2 ----------------
__global__ __launch_bounds__(256) void gate_kernel(
    const float* __restrict__ g1, const float* __restrict__ Wg2,
    const float* __restrict__ bg2, float* __restrict__ gate)
{
  int lane = threadIdx.x & 63;
  int wv = threadIdx.x >> 6;
  int stride = gridDim.x * 4;
  float w0 = Wg2[lane];
  float w1 = Wg2[64 + lane];
  float bb = bg2[0];
  for (int n = blockIdx.x * 4 + wv; n < N_NODES; n += stride) {
    float v = g1[(size_t)n * 128 + lane] * w0 + g1[(size_t)n * 128 + 64 + lane] * w1;
#pragma unroll
    for (int o = 1; o < 64; o <<= 1) v += __shfl_xor(v, o);
    if (lane == 0) gate[n] = v + bb;
  }
}

// ---------------- global attention pooling per graph ----------------
__global__ __launch_bounds__(64) void pool_kernel(
    const float* __restrict__ gate, const float* __restrict__ h,
    const int* __restrict__ brp, float* __restrict__ pooled)
{
  int b = blockIdx.x;
  int lane = threadIdx.x;
  int s = brp[b], e = brp[b + 1];
  float m = -__builtin_inff();
  for (int i = s + lane; i < e; i += 64) m = fmaxf(m, gate[i]);
#pragma unroll
  for (int o = 1; o < 64; o <<= 1) m = fmaxf(m, __shfl_xor(m, o));
  float d = 0.f;
  for (int i = s + lane; i < e; i += 64) d += __expf(gate[i] - m);
#pragma unroll
  for (int o = 1; o < 64; o <<= 1) d += __shfl_xor(d, o);
  float inv = 1.f / (d + 1e-16f);
  int c0 = lane * 4;
  float acc[4] = {0.f, 0.f, 0.f, 0.f};
  for (int i = s; i < e; ++i) {
    float w = __expf(gate[i] - m) * inv;
    float4 hv = *(const float4*)(h + (size_t)i * HIDDEN + c0);
    acc[0] = fmaf(w, hv.x, acc[0]);
    acc[1] = fmaf(w, hv.y, acc[1]);
    acc[2] = fmaf(w, hv.z, acc[2]);
    acc[3] = fmaf(w, hv.w, acc[3]);
  }
  float4 outv = make_float4(acc[0], acc[1], acc[2], acc[3]);
  *(float4*)(pooled + (size_t)b * HIDDEN + c0) = outv;
}

// ---------------- final: out[b] = r3[b,:] . W4 + b4 (f32 store) ----------------
__global__ __launch_bounds__(256) void out_kernel(
    const float* __restrict__ r3, const float* __restrict__ W4,
    const float* __restrict__ b4, float* __restrict__ out)
{
  int lane = threadIdx.x & 63;
  int wv = threadIdx.x >> 6;
  int b = blockIdx.x * 4 + wv;
  if (b >= N_B) return;
  float v = r3[(size_t)b * 64 + lane] * W4[lane];
#pragma unroll
  for (int o = 1; o < 64; o <<= 1) v += __shfl_xor(v, o);
  if (lane == 0) out[b] = v + b4[0];
}

extern "C" void kernel_launch(void* const* d_in, const int* in_sizes, int n_in,
                              void* d_out, int out_size, void* d_ws, size_t ws_size,
                              hipStream_t stream)
{
  const float* x    = (const float*)d_in[0];
  const int* ei     = (const int*)d_in[1];
  const float* ea   = (const float*)d_in[2];
  const int* batch  = (const int*)d_in[3];
  const float* W_in = (const float*)d_in[4];
  const float* b_in = (const float*)d_in[5];
  const float* Wl   = (const float*)d_in[6];
  const float* Wr   = (const float*)d_in[7];
  const float* We   = (const float*)d_in[8];
  const float* att  = (const float*)d_in[9];
  const float* bgat = (const float*)d_in[10];
  const float* Wg1  = (const float*)d_in[11];
  const float* bg1  = (const float*)d_in[12];
  const float* Wg2  = (const float*)d_in[13];
  const float* bg2  = (const float*)d_in[14];
  const float* W1   = (const float*)d_in[15];
  const float* b1   = (const float*)d_in[16];
  const float* W2   = (const float*)d_in[17];
  const float* b2   = (const float*)d_in[18];
  const float* W3   = (const float*)d_in[19];
  const float* b3   = (const float*)d_in[20];
  const float* W4   = (const float*)d_in[21];
  const float* b4   = (const float*)d_in[22];
  float* out = (float*)d_out;

  char* ws = (char*)d_ws;
  size_t off = 0;
  auto alloc = [&](size_t bytes) -> char* {
    char* p = ws + off;
    off += (bytes + 255) & ~(size_t)255;
    return p;
  };
  float* h            = (float*)alloc((size_t)N_NODES * HIDDEN * 4);           // 102.4 MB
  float* xl           = (float*)alloc((size_t)N_NODES * HIDDEN * 4);           // 102.4 MB
  unsigned short* xrb = (unsigned short*)alloc((size_t)N_NODES * HIDDEN * 2);  // 51.2 MB
  int* deg       = (int*)alloc((size_t)N_NODES * 4);
  int* rowptr    = (int*)alloc((size_t)(N_NODES + 1) * 4);
  int* cursor    = (int*)alloc((size_t)N_NODES * 4);
  int* csr       = (int*)alloc((size_t)N_TOT * 4);
  int* brp       = (int*)alloc((size_t)(N_B + 1) * 4);
  float* macc    = (float*)alloc(64);
  float* ep_self = (float*)alloc(4 * 256 * 4);
  // total ~258.6 MB < 256 MiB = 268.4 MB  ✓

  // aliases into dead regions:
  float* xpad = xl;                       // [N,96] f32, pre-layer0 only
  float* g1   = (float*)xrb;              // [N,128] f32 (51.2 MB, exact fit), post-layers
  float* gate   = xl;                     // [N] f32, post-layers (xl dead)
  float* pooled = xl + 1000000;           // [B,256] f32
  float* r1     = xl + 3000000;           // [B,256] f32
  float* r2     = xl + 5000000;           // [B,128] f32
  float* r3     = xl + 6000000;           // [B,64]  f32

  if (ws_size < off) {  // never expected (256 MiB measured round 10)
    hipMemsetAsync(d_out, 0, (size_t)out_size * 4, stream);
    return;
  }

  zero_kernel<<<391, 256, 0, stream>>>(deg, cursor, macc);
  mean_kernel<<<256, 256, 0, stream>>>(ea, macc);
  epself_kernel<<<4, 256, 0, stream>>>(macc, We, ep_self);
  count_kernel<<<1250, 256, 0, stream>>>(ei, deg);
  scan_kernel<<<1, 1024, 0, stream>>>(deg, rowptr);
  scatter_kernel<<<1250, 256, 0, stream>>>(ei, rowptr, cursor, csr);
  brp_kernel<<<512, 256, 0, stream>>>(batch, brp);
  convx_kernel<<<4096, 256, 0, stream>>>(x, xpad);

  // input projection: h = elu((x @ W_in + b_in) * BN_S), K padded to 96 (KB=75)
  gemm_kernel<<<dim3(4, 1563), 256, 0, stream>>>(xpad, W_in, b_in, h,
                                                 N_NODES, 256, 96, 75, 2, BN_S, 0);

  for (int i = 0; i < 4; ++i) {
    gemm_kernel<<<dim3(4, 1563), 256, 0, stream>>>(h, Wl + (size_t)i * 65536, nullptr, xl,
                                                   N_NODES, 256, 256, 256, 0, 1.f, 0);
    gemm_kernel<<<dim3(4, 1563), 256, 0, stream>>>(h, Wr + (size_t)i * 65536, nullptr, xrb,
                                                   N_NODES, 256, 256, 256, 0, 1.f, 1);
    attn_kernel<<<25000, 256, 0, stream>>>(xl, xrb, h, ei, ea,
                                           We + (size_t)i * 2560, att + (size_t)i * 256,
                                           bgat + (size_t)i * 256, ep_self + (size_t)i * 256,
                                           rowptr, csr);
  }

  // pooling gate (g1 into dead xr region; gate/pooled into dead xl region)
  gemm_kernel<<<dim3(2, 1563), 256, 0, stream>>>(h, Wg1, bg1, g1,
                                                 N_NODES, 128, 256, 256, 1, 1.f, 0);
  gate_kernel<<<512, 256, 0, stream>>>(g1, Wg2, bg2, gate);
  pool_kernel<<<N_B, 64, 0, stream>>>(gate, h, brp, pooled);

  // readout MLP
  gemm_kernel<<<dim3(4, 64), 256, 0, stream>>>(pooled, W1, b1, r1, N_B, 256, 256, 256, 1, BN_S, 0);
  gemm_kernel<<<dim3(2, 64), 256, 0, stream>>>(r1, W2, b2, r2, N_B, 128, 256, 256, 1, BN_S, 0);
  gemm_kernel<<<dim3(1, 64), 256, 0, stream>>>(r2, W3, b3, r3, N_B, 64, 128, 128, 1, 1.f, 0);
  out_kernel<<<1024, 256, 0, stream>>>(r3, W4, b4, out);
}

// Round 15
// 1815.483 us; speedup vs baseline: 2.6485x; 1.4949x over previous
//
#include <hip/hip_runtime.h>

#define N_NODES 100000
#define N_EDGES 220000
#define N_TOT   320000   // E + N self loops
#define N_B     4096
#define HIDDEN  256
#define BN_S    0.9999950000374997f
#define LDSW    40       // LDS row stride in bf16 elems (80 B, 16B-aligned, conflict-free)

typedef __attribute__((ext_vector_type(8))) short bf16x8;
typedef __attribute__((ext_vector_type(4))) float f32x4;

__device__ __forceinline__ float bf2f(unsigned short u) {
  return __uint_as_float(((unsigned int)u) << 16);
}
__device__ __forceinline__ unsigned short f2bf(float f) {
  unsigned int x = __float_as_uint(f);
  unsigned int lsb = (x >> 16) & 1u;
  x += 0x7fffu + lsb;
  return (unsigned short)(x >> 16);
}

// ---------------- zero-init of counters ----------------
__global__ void zero_kernel(int* __restrict__ deg, int* __restrict__ cursor, float* __restrict__ macc) {
  int i = blockIdx.x * blockDim.x + threadIdx.x;
  if (i < N_NODES) { deg[i] = 0; cursor[i] = 0; }
  if (i < 16) macc[i] = 0.f;
}

// ---------------- mean of edge_attr ----------------
__global__ void mean_kernel(const float* __restrict__ ea, float* __restrict__ macc) {
  int lane = threadIdx.x & 63;
  float loc[10];
#pragma unroll
  for (int k = 0; k < 10; ++k) loc[k] = 0.f;
  for (int e = blockIdx.x * blockDim.x + threadIdx.x; e < N_EDGES; e += gridDim.x * blockDim.x) {
    const float* p = ea + (size_t)e * 10;
#pragma unroll
    for (int k = 0; k < 10; ++k) loc[k] += p[k];
  }
#pragma unroll
  for (int k = 0; k < 10; ++k) {
    float v = loc[k];
#pragma unroll
    for (int o = 1; o < 64; o <<= 1) v += __shfl_xor(v, o);
    if (lane == 0) atomicAdd(&macc[k], v);
  }
}

__global__ void epself_kernel(const float* __restrict__ macc, const float* __restrict__ We,
                              float* __restrict__ ep_self) {
  int i = blockIdx.x;
  int c = threadIdx.x;
  const float invE = 1.f / (float)N_EDGES;
  float s = 0.f;
#pragma unroll
  for (int k = 0; k < 10; ++k)
    s += (macc[k] * invE) * We[(size_t)i * 2560 + k * 256 + c];
  ep_self[i * 256 + c] = s;
}

// ---------------- CSR build ----------------
__global__ void count_kernel(const int* __restrict__ ei, int* __restrict__ deg) {
  for (int e = blockIdx.x * blockDim.x + threadIdx.x; e < N_TOT; e += gridDim.x * blockDim.x) {
    int t;
    if (e < N_EDGES) t = ei[N_EDGES + e];
    else             t = e - N_EDGES;
    atomicAdd(&deg[t], 1);
  }
}

__global__ __launch_bounds__(1024) void scan_kernel(const int* __restrict__ deg, int* __restrict__ rowptr) {
  __shared__ int buf[1024];
  __shared__ int carry;
  int t = threadIdx.x;
  if (t == 0) { rowptr[0] = 0; carry = 0; }
  __syncthreads();
  for (int base = 0; base < N_NODES; base += 1024) {
    int i = base + t;
    int v = (i < N_NODES) ? deg[i] : 0;
    buf[t] = v;
    __syncthreads();
    for (int off = 1; off < 1024; off <<= 1) {
      int add = (t >= off) ? buf[t - off] : 0;
      __syncthreads();
      buf[t] += add;
      __syncthreads();
    }
    int outv = buf[t] + carry;
    if (i < N_NODES) rowptr[i + 1] = outv;
    __syncthreads();
    if (t == 1023) carry = outv;
    __syncthreads();
  }
}

__global__ void scatter_kernel(const int* __restrict__ ei, const int* __restrict__ rowptr,
                               int* __restrict__ cursor, int* __restrict__ csr) {
  for (int e = blockIdx.x * blockDim.x + threadIdx.x; e < N_TOT; e += gridDim.x * blockDim.x) {
    int t;
    if (e < N_EDGES) t = ei[N_EDGES + e];
    else             t = e - N_EDGES;
    int pos = atomicAdd(&cursor[t], 1);
    csr[rowptr[t] + pos] = e;
  }
}

__global__ void brp_kernel(const int* __restrict__ batch, int* __restrict__ brp) {
  for (int i = blockIdx.x * blockDim.x + threadIdx.x; i < N_NODES; i += gridDim.x * blockDim.x) {
    int bi = batch[i];
    int bp = (i == 0) ? -1 : batch[i - 1];
    for (int b = bp + 1; b <= bi; ++b) brp[b] = i;
    if (i == N_NODES - 1) {
      for (int b = bi + 1; b <= N_B; ++b) brp[b] = N_NODES;
    }
  }
}

// ---------------- x -> padded bf16 [N,96] ----------------
__global__ void convx_kernel(const float* __restrict__ x, unsigned short* __restrict__ xp) {
  int total = N_NODES * 96;
  for (int idx = blockIdx.x * blockDim.x + threadIdx.x; idx < total; idx += gridDim.x * blockDim.x) {
    int nn = idx / 96;
    int j = idx - nn * 96;
    unsigned short v = 0;
    if (j < 75) v = f2bf(x[(size_t)nn * 75 + j]);
    xp[idx] = v;
  }
}

// ---------------- weight transpose+bf16: dst[n*Kp+k] = src[k*N+n] (0 beyond K) ----------------
__global__ void wt_kernel(const float* __restrict__ src, unsigned short* __restrict__ dst,
                          int K, int Kp, int N) {
  int idx = blockIdx.x * blockDim.x + threadIdx.x;
  int total = N * Kp;
  if (idx >= total) return;
  int n = idx / Kp, k = idx - n * Kp;
  dst[idx] = (k < K) ? f2bf(src[(size_t)k * N + n]) : (unsigned short)0;
}

// ---------------- bf16 MFMA GEMM: C = act((A @ Bt^T + bias)*scale) ----------------
// A [M,K] bf16 row-major (K mult of 32); Bt [Ncol,K] bf16 (pre-transposed weights).
// Dual store: Cf (f32) and/or Cb (bf16), either may be null. act 0=none 1=relu 2=elu.
__global__ __launch_bounds__(256) void gemm_mfma(
    const unsigned short* __restrict__ A, const unsigned short* __restrict__ Bt,
    const float* __restrict__ bias, float* __restrict__ Cf, unsigned short* __restrict__ Cb,
    int M, int Ncol, int K, int act, float scale)
{
  __shared__ unsigned short As[128 * LDSW];
  __shared__ unsigned short Bs[128 * LDSW];
  const int tid = threadIdx.x;
  const int wave = tid >> 6;
  const int lane = tid & 63;
  const int col0 = blockIdx.x * 128;
  const int row0 = blockIdx.y * 128;
  const int wrow = (wave >> 1) * 64;
  const int wcol = (wave & 1) * 64;
  const int lrow = lane & 15;
  const int quad = lane >> 4;

  f32x4 acc[4][4] = {};

  const int srow = tid >> 1;          // 0..127
  const int shalf = (tid & 1) * 16;   // 0 or 16 (bf16 elems)

  for (int k0 = 0; k0 < K; k0 += 32) {
    {
      int gr = row0 + srow;
      uint4 a0 = {0, 0, 0, 0}, a1 = {0, 0, 0, 0};
      if (gr < M) {
        const unsigned short* src = A + (size_t)gr * K + k0 + shalf;
        a0 = *(const uint4*)(src);
        a1 = *(const uint4*)(src + 8);
      }
      *(uint4*)(&As[srow * LDSW + shalf]) = a0;
      *(uint4*)(&As[srow * LDSW + shalf + 8]) = a1;
      const unsigned short* srcb = Bt + (size_t)(col0 + srow) * K + k0 + shalf;
      *(uint4*)(&Bs[srow * LDSW + shalf]) = *(const uint4*)(srcb);
      *(uint4*)(&Bs[srow * LDSW + shalf + 8]) = *(const uint4*)(srcb + 8);
    }
    __syncthreads();
    bf16x8 afr[4], bfr[4];
#pragma unroll
    for (int mt = 0; mt < 4; ++mt)
      afr[mt] = *(const bf16x8*)(&As[(wrow + mt * 16 + lrow) * LDSW + quad * 8]);
#pragma unroll
    for (int nt = 0; nt < 4; ++nt)
      bfr[nt] = *(const bf16x8*)(&Bs[(wcol + nt * 16 + lrow) * LDSW + quad * 8]);
#pragma unroll
    for (int mt = 0; mt < 4; ++mt)
#pragma unroll
      for (int nt = 0; nt < 4; ++nt)
        acc[mt][nt] = __builtin_amdgcn_mfma_f32_16x16x32_bf16(afr[mt], bfr[nt], acc[mt][nt], 0, 0, 0);
    __syncthreads();
  }

#pragma unroll
  for (int mt = 0; mt < 4; ++mt) {
#pragma unroll
    for (int nt = 0; nt < 4; ++nt) {
      int gcol = col0 + wcol + nt * 16 + lrow;
      float bv = bias ? bias[gcol] : 0.f;
#pragma unroll
      for (int r = 0; r < 4; ++r) {
        int grow = row0 + wrow + mt * 16 + quad * 4 + r;
        if (grow >= M) continue;
        float v = (acc[mt][nt][r] + bv) * scale;
        if (act == 1) v = fmaxf(v, 0.f);
        else if (act == 2) v = (v > 0.f) ? v : (__expf(v) - 1.f);
        if (Cf) Cf[(size_t)grow * Ncol + gcol] = v;
        if (Cb) Cb[(size_t)grow * Ncol + gcol] = f2bf(v);
      }
    }
  }
}

// ---------------- f32 GEMM for the tiny readout layers ----------------
__global__ __launch_bounds__(256) void gemm_f32(
    const float* __restrict__ A, const float* __restrict__ B,
    const float* __restrict__ bias, float* __restrict__ C,
    int M, int Ncol, int K, int act, float scale)
{
  __shared__ float As[32][68];
  __shared__ float Bs[32][68];
  const int tid = threadIdx.x;
  const int tx = tid & 15, ty = tid >> 4;
  const int col0 = blockIdx.x * 64;
  const int row0 = blockIdx.y * 64;
  float acc[4][4];
#pragma unroll
  for (int i = 0; i < 4; ++i)
#pragma unroll
    for (int j = 0; j < 4; ++j) acc[i][j] = 0.f;

  const int ar = tid >> 3;
  const int ak = (tid & 7) * 4;
  const int bk = tid >> 4;
  const int bc = (tid & 15) * 4;

  for (int k0 = 0; k0 < K; k0 += 32) {
#pragma unroll
    for (int p = 0; p < 2; ++p) {
      int r = ar + p * 32;
      int grow = row0 + r;
      float4 v = make_float4(0.f, 0.f, 0.f, 0.f);
      if (grow < M) v = *(const float4*)(A + (size_t)grow * K + k0 + ak);
      As[ak + 0][r] = v.x; As[ak + 1][r] = v.y; As[ak + 2][r] = v.z; As[ak + 3][r] = v.w;
    }
#pragma unroll
    for (int p = 0; p < 2; ++p) {
      int kk = bk + p * 16;
      float4 v = *(const float4*)(B + (size_t)(k0 + kk) * Ncol + col0 + bc);
      *(float4*)(&Bs[kk][bc]) = v;
    }
    __syncthreads();
#pragma unroll
    for (int kk = 0; kk < 32; ++kk) {
      float4 a = *(const float4*)(&As[kk][ty * 4]);
      float4 b = *(const float4*)(&Bs[kk][tx * 4]);
      float av[4] = {a.x, a.y, a.z, a.w};
      float bv[4] = {b.x, b.y, b.z, b.w};
#pragma unroll
      for (int i = 0; i < 4; ++i)
#pragma unroll
        for (int j = 0; j < 4; ++j) acc[i][j] = fmaf(av[i], bv[j], acc[i][j]);
    }
    __syncthreads();
  }
  float bvals[4] = {0.f, 0.f, 0.f, 0.f};
  if (bias) {
#pragma unroll
    for (int j = 0; j < 4; ++j) bvals[j] = bias[col0 + tx * 4 + j];
  }
#pragma unroll
  for (int i = 0; i < 4; ++i) {
    int r = row0 + ty * 4 + i;
    if (r >= M) continue;
    float4 outv;
    float* o = (float*)&outv;
#pragma unroll
    for (int j = 0; j < 4; ++j) {
      float v = (acc[i][j] + bvals[j]) * scale;
      if (act == 1) v = fmaxf(v, 0.f);
      else if (act == 2) v = (v > 0.f) ? v : (__expf(v) - 1.f);
      o[j] = v;
    }
    *(float4*)(C + (size_t)r * Ncol + col0 + tx * 4) = outv;
  }
}

// ---------------- fused GATv2 attention + aggregate + BN/ELU/residual ----------------
// one wave per node; lane l owns flat channels [4l,4l+4); head = l>>3
// xl/xr bf16; h f32 (residual) + hb bf16 shadow written for the next GEMM.
__global__ __launch_bounds__(256) void attn_kernel(
    const unsigned short* __restrict__ xl, const unsigned short* __restrict__ xr,
    float* __restrict__ h, unsigned short* __restrict__ hb,
    const int* __restrict__ ei, const float* __restrict__ eattr,
    const float* __restrict__ We, const float* __restrict__ att,
    const float* __restrict__ bgat, const float* __restrict__ ep_self,
    const int* __restrict__ rowptr, const int* __restrict__ csr)
{
  const int lane = threadIdx.x & 63;
  const int wv = threadIdx.x >> 6;
  const int n = blockIdx.x * 4 + wv;
  if (n >= N_NODES) return;
  const int c0 = lane * 4;

  float xrn[4];
  {
    ushort4 u = *(const ushort4*)(xr + (size_t)n * HIDDEN + c0);
    xrn[0] = bf2f(u.x); xrn[1] = bf2f(u.y); xrn[2] = bf2f(u.z); xrn[3] = bf2f(u.w);
  }
  float4 attf4 = *(const float4*)(att + c0);
  float attf[4] = {attf4.x, attf4.y, attf4.z, attf4.w};
  float wef[10][4];
#pragma unroll
  for (int k = 0; k < 10; ++k) {
    float4 w4 = *(const float4*)(We + k * 256 + c0);
    wef[k][0] = w4.x; wef[k][1] = w4.y; wef[k][2] = w4.z; wef[k][3] = w4.w;
  }
  float4 eps = *(const float4*)(ep_self + c0);

  float m = -__builtin_inff();
  float d = 0.f;
  float a0 = 0.f, a1 = 0.f, a2 = 0.f, a3 = 0.f;
  const int s = rowptr[n], e = rowptr[n + 1];
  for (int idx = s; idx < e; ++idx) {
    int eid = csr[idx];
    int srcn;
    float ep0, ep1, ep2, ep3;
    if (eid < N_EDGES) {
      srcn = ei[eid];
      const float* eap = eattr + (size_t)eid * 10;
      ep0 = 0.f; ep1 = 0.f; ep2 = 0.f; ep3 = 0.f;
#pragma unroll
      for (int k = 0; k < 10; ++k) {
        float eak = eap[k];
        ep0 = fmaf(eak, wef[k][0], ep0);
        ep1 = fmaf(eak, wef[k][1], ep1);
        ep2 = fmaf(eak, wef[k][2], ep2);
        ep3 = fmaf(eak, wef[k][3], ep3);
      }
    } else {
      srcn = eid - N_EDGES;
      ep0 = eps.x; ep1 = eps.y; ep2 = eps.z; ep3 = eps.w;
    }
    float x0, x1, x2, x3;
    {
      ushort4 u = *(const ushort4*)(xl + (size_t)srcn * HIDDEN + c0);
      x0 = bf2f(u.x); x1 = bf2f(u.y); x2 = bf2f(u.z); x3 = bf2f(u.w);
    }
    float s0 = x0 + xrn[0] + ep0;
    float s1 = x1 + xrn[1] + ep1;
    float s2 = x2 + xrn[2] + ep2;
    float s3 = x3 + xrn[3] + ep3;
    s0 = (s0 > 0.f) ? s0 : 0.2f * s0;
    s1 = (s1 > 0.f) ? s1 : 0.2f * s1;
    s2 = (s2 > 0.f) ? s2 : 0.2f * s2;
    s3 = (s3 > 0.f) ? s3 : 0.2f * s3;
    float part = s0 * attf[0] + s1 * attf[1] + s2 * attf[2] + s3 * attf[3];
    part += __shfl_xor(part, 1);
    part += __shfl_xor(part, 2);
    part += __shfl_xor(part, 4);
    float logit = part;
    float mn = fmaxf(m, logit);
    float sc = __expf(m - mn);
    float w = __expf(logit - mn);
    d = d * sc + w;
    a0 = a0 * sc + w * x0;
    a1 = a1 * sc + w * x1;
    a2 = a2 * sc + w * x2;
    a3 = a3 * sc + w * x3;
    m = mn;
  }
  float inv = 1.f / (d + 1e-16f);
  float4 bg = *(const float4*)(bgat + c0);
  float4 hold = *(const float4*)(h + (size_t)n * HIDDEN + c0);
  float ov[4] = {a0 * inv, a1 * inv, a2 * inv, a3 * inv};
  float bgv[4] = {bg.x, bg.y, bg.z, bg.w};
  float hv[4] = {hold.x, hold.y, hold.z, hold.w};
  float4 res;
  float* rp = (float*)&res;
  ushort4 resb;
  unsigned short* rb = (unsigned short*)&resb;
#pragma unroll
  for (int j = 0; j < 4; ++j) {
    float v = (ov[j] + bgv[j]) * BN_S;
    v = (v > 0.f) ? v : (__expf(v) - 1.f);
    float nv = v + hv[j];
    rp[j] = nv;
    rb[j] = f2bf(nv);
  }
  *(float4*)(h + (size_t)n * HIDDEN + c0) = res;
  *(ushort4*)(hb + (size_t)n * HIDDEN + c0) = resb;
}

// ---------------- gate = relu_g1 @ Wg2 + bg2 ----------------
__global__ __launch_bounds__(256) void gate_kernel(
    const float* __restrict__ g1, const float* __restrict__ Wg2,
    const float* __restrict__ bg2, float* __restrict__ gate)
{
  int lane = threadIdx.x & 63;
  int wv = threadIdx.x >> 6;
  int stride = gridDim.x * 4;
  float w0 = Wg2[lane];
  float w1 = Wg2[64 + lane];
  float bb = bg2[0];
  for (int n = blockIdx.x * 4 + wv; n < N_NODES; n += stride) {
    float v = g1[(size_t)n * 128 + lane] * w0 + g1[(size_t)n * 128 + 64 + lane] * w1;
#pragma unroll
    for (int o = 1; o < 64; o <<= 1) v += __shfl_xor(v, o);
    if (lane == 0) gate[n] = v + bb;
  }
}

// ---------------- global attention pooling per graph ----------------
__global__ __launch_bounds__(64) void pool_kernel(
    const float* __restrict__ gate, const float* __restrict__ h,
    const int* __restrict__ brp, float* __restrict__ pooled)
{
  int b = blockIdx.x;
  int lane = threadIdx.x;
  int s = brp[b], e = brp[b + 1];
  float m = -__builtin_inff();
  for (int i = s + lane; i < e; i += 64) m = fmaxf(m, gate[i]);
#pragma unroll
  for (int o = 1; o < 64; o <<= 1) m = fmaxf(m, __shfl_xor(m, o));
  float d = 0.f;
  for (int i = s + lane; i < e; i += 64) d += __expf(gate[i] - m);
#pragma unroll
  for (int o = 1; o < 64; o <<= 1) d += __shfl_xor(d, o);
  float inv = 1.f / (d + 1e-16f);
  int c0 = lane * 4;
  float acc[4] = {0.f, 0.f, 0.f, 0.f};
  for (int i = s; i < e; ++i) {
    float w = __expf(gate[i] - m) * inv;
    float4 hv = *(const float4*)(h + (size_t)i * HIDDEN + c0);
    acc[0] = fmaf(w, hv.x, acc[0]);
    acc[1] = fmaf(w, hv.y, acc[1]);
    acc[2] = fmaf(w, hv.z, acc[2]);
    acc[3] = fmaf(w, hv.w, acc[3]);
  }
  float4 outv = make_float4(acc[0], acc[1], acc[2], acc[3]);
  *(float4*)(pooled + (size_t)b * HIDDEN + c0) = outv;
}

// ---------------- final: out[b] = r3[b,:] . W4 + b4 ----------------
__global__ __launch_bounds__(256) void out_kernel(
    const float* __restrict__ r3, const float* __restrict__ W4,
    const float* __restrict__ b4, float* __restrict__ out)
{
  int lane = threadIdx.x & 63;
  int wv = threadIdx.x >> 6;
  int b = blockIdx.x * 4 + wv;
  if (b >= N_B) return;
  float v = r3[(size_t)b * 64 + lane] * W4[lane];
#pragma unroll
  for (int o = 1; o < 64; o <<= 1) v += __shfl_xor(v, o);
  if (lane == 0) out[b] = v + b4[0];
}

extern "C" void kernel_launch(void* const* d_in, const int* in_sizes, int n_in,
                              void* d_out, int out_size, void* d_ws, size_t ws_size,
                              hipStream_t stream)
{
  const float* x    = (const float*)d_in[0];
  const int* ei     = (const int*)d_in[1];
  const float* ea   = (const float*)d_in[2];
  const int* batch  = (const int*)d_in[3];
  const float* W_in = (const float*)d_in[4];
  const float* b_in = (const float*)d_in[5];
  const float* Wl   = (const float*)d_in[6];
  const float* Wr   = (const float*)d_in[7];
  const float* We   = (const float*)d_in[8];
  const float* att  = (const float*)d_in[9];
  const float* bgat = (const float*)d_in[10];
  const float* Wg1  = (const float*)d_in[11];
  const float* bg1  = (const float*)d_in[12];
  const float* Wg2  = (const float*)d_in[13];
  const float* bg2  = (const float*)d_in[14];
  const float* W1   = (const float*)d_in[15];
  const float* b1   = (const float*)d_in[16];
  const float* W2   = (const float*)d_in[17];
  const float* b2   = (const float*)d_in[18];
  const float* W3   = (const float*)d_in[19];
  const float* b3   = (const float*)d_in[20];
  const float* W4   = (const float*)d_in[21];
  const float* b4   = (const float*)d_in[22];
  float* out = (float*)d_out;

  char* ws = (char*)d_ws;
  size_t off = 0;
  auto alloc = [&](size_t bytes) -> char* {
    char* p = ws + off;
    off += (bytes + 255) & ~(size_t)255;
    return p;
  };
  float* h            = (float*)alloc((size_t)N_NODES * HIDDEN * 4);           // 102.4 MB
  unsigned short* hb  = (unsigned short*)alloc((size_t)N_NODES * HIDDEN * 2);  // 51.2 MB
  unsigned short* xlb = (unsigned short*)alloc((size_t)N_NODES * HIDDEN * 2);  // 51.2 MB
  unsigned short* xrb = (unsigned short*)alloc((size_t)N_NODES * HIDDEN * 2);  // 51.2 MB
  int* deg       = (int*)alloc((size_t)N_NODES * 4);
  int* rowptr    = (int*)alloc((size_t)(N_NODES + 1) * 4);
  int* cursor    = (int*)alloc((size_t)N_NODES * 4);
  int* csr       = (int*)alloc((size_t)N_TOT * 4);
  int* brp       = (int*)alloc((size_t)(N_B + 1) * 4);
  float* macc    = (float*)alloc(64);
  float* ep_self = (float*)alloc(4 * 256 * 4);
  unsigned short* Wint  = (unsigned short*)alloc(256 * 96 * 2);       // [256][96]
  unsigned short* Wlt   = (unsigned short*)alloc(4 * 256 * 256 * 2);  // [i][256][256]
  unsigned short* Wrt   = (unsigned short*)alloc(4 * 256 * 256 * 2);
  unsigned short* Wg1t  = (unsigned short*)alloc(128 * 256 * 2);      // [128][256]
  // total ≈ 259.7 MB < 268.4 MB ws  ✓

  // aliases into dead regions:
  unsigned short* xpad = xlb;            // [N,96] bf16, pre-layer0 only
  float* g1     = (float*)xlb;           // [N,128] f32 (51.2 MB exact), post-layers
  float* gate   = (float*)xrb;           // [N] f32, post-layers
  float* pooled = (float*)xrb + 1000000; // [B,256] f32
  float* r1     = (float*)xrb + 3000000; // [B,256] f32
  float* r2     = (float*)xrb + 5000000; // [B,128] f32
  float* r3     = (float*)xrb + 6000000; // [B,64]  f32

  if (ws_size < off) {
    hipMemsetAsync(d_out, 0, (size_t)out_size * 4, stream);
    return;
  }

  zero_kernel<<<391, 256, 0, stream>>>(deg, cursor, macc);
  mean_kernel<<<256, 256, 0, stream>>>(ea, macc);
  epself_kernel<<<4, 256, 0, stream>>>(macc, We, ep_self);
  count_kernel<<<1250, 256, 0, stream>>>(ei, deg);
  scan_kernel<<<1, 1024, 0, stream>>>(deg, rowptr);
  scatter_kernel<<<1250, 256, 0, stream>>>(ei, rowptr, cursor, csr);
  brp_kernel<<<512, 256, 0, stream>>>(batch, brp);

  // weight conversions (transpose + bf16)
  wt_kernel<<<(256 * 96 + 255) / 256, 256, 0, stream>>>(W_in, Wint, 75, 96, 256);
  for (int i = 0; i < 4; ++i) {
    wt_kernel<<<256, 256, 0, stream>>>(Wl + (size_t)i * 65536, Wlt + (size_t)i * 65536, 256, 256, 256);
    wt_kernel<<<256, 256, 0, stream>>>(Wr + (size_t)i * 65536, Wrt + (size_t)i * 65536, 256, 256, 256);
  }
  wt_kernel<<<128, 256, 0, stream>>>(Wg1, Wg1t, 256, 256, 128);
  convx_kernel<<<4096, 256, 0, stream>>>(x, xpad);

  // input projection: h = elu((x @ W_in + b_in) * BN_S)  [MFMA, K=96]
  gemm_mfma<<<dim3(2, 782), 256, 0, stream>>>(xpad, Wint, b_in, h, hb,
                                              N_NODES, 256, 96, 2, BN_S);

  for (int i = 0; i < 4; ++i) {
    gemm_mfma<<<dim3(2, 782), 256, 0, stream>>>(hb, Wlt + (size_t)i * 65536, nullptr,
                                                nullptr, xlb, N_NODES, 256, 256, 0, 1.f);
    gemm_mfma<<<dim3(2, 782), 256, 0, stream>>>(hb, Wrt + (size_t)i * 65536, nullptr,
                                                nullptr, xrb, N_NODES, 256, 256, 0, 1.f);
    attn_kernel<<<25000, 256, 0, stream>>>(xlb, xrb, h, hb, ei, ea,
                                           We + (size_t)i * 2560, att + (size_t)i * 256,
                                           bgat + (size_t)i * 256, ep_self + (size_t)i * 256,
                                           rowptr, csr);
  }

  // pooling gate: g1 = relu(hb @ Wg1 + bg1)  [MFMA, writes into dead xl region]
  gemm_mfma<<<dim3(1, 782), 256, 0, stream>>>(hb, Wg1t, bg1, g1, nullptr,
                                              N_NODES, 128, 256, 1, 1.f);
  gate_kernel<<<512, 256, 0, stream>>>(g1, Wg2, bg2, gate);
  pool_kernel<<<N_B, 64, 0, stream>>>(gate, h, brp, pooled);

  // readout MLP (f32, tiny)
  gemm_f32<<<dim3(4, 64), 256, 0, stream>>>(pooled, W1, b1, r1, N_B, 256, 256, 1, BN_S);
  gemm_f32<<<dim3(2, 64), 256, 0, stream>>>(r1, W2, b2, r2, N_B, 128, 256, 1, BN_S);
  gemm_f32<<<dim3(1, 64), 256, 0, stream>>>(r2, W3, b3, r3, N_B, 64, 128, 1, 1.f);
  out_kernel<<<1024, 256, 0, stream>>>(r3, W4, b4, out);
}